// Round 4
// baseline (670.105 us; speedup 1.0000x reference)
//
#include <hip/hip_runtime.h>

// ============================================================================
// SE3 two-layer point kernel, MI355X (gfx950)
// Output: (36,36,256,256) fp32, ~340 MB -> HBM-write floor ~52us (+212us
// harness re-poison fill we cannot control).
//
// R4 change: FIT THE LIVE SET IN 64 VGPRs BY CONSTRUCTION (heavy paths).
//   History: VGPR_Count pinned at 64-68 across launch_bounds variants and
//   asm-pinning; zero scratch; VALU issue 4-8x static FMA count. Theory: the
//   allocator handles the ~110-value live set (Y[25]+c[50]+...) via AGPR
//   shuttling (v_accvgpr_* = VALU, invisible in memory counters) + sinking
//   the c[t][j] chains into the 25-iter (a,b) loop. Forcing more VGPRs
//   failed twice -> instead SHRINK the live set:
//     * drop the c[10][NJ] array (50 regs, its biggest block);
//     * per (a,b): Kt[r][j] = wv[r]*K[j]  (4*NJ regs), then
//       h[t] = b0[t] + sum_{j,r} w0[t, r*NJ+j] * Kt[r][j]
//       with w0 read via the scalar path (SGPR operand, zero VGPR cost).
//   Live set: Y(25)+Kt(20)+h(10)+wv(4) ~ 60 -> fits 64. 1.45x FMAs (FMA
//   floor only ~14us) for an honest register fit. Heavy paths (4,5,7,8)
//   only; light paths keep the bit-identical c-form.
//   Heavy-path numerics: radial-sum reassociation only (~1e-6 rel).
// ============================================================================

#define DEV __device__ __forceinline__

// ----- compile-time path metadata: path p = lo*3 + li ------------------------
constexpr int PW0[9]   = {0,40,80,120,160,280,400,440,560};   // weight_0 offsets
constexpr int PQOFF[9] = {0,1,10,35,44,125,350,375,600};      // Q table base (floats)
constexpr int YBASE[5] = {0,1,4,9,16};                        // Y row offset per J

__host__ __device__ constexpr int qlocal(int DO, int DI, int JS, int j) {
  int o = 0;
  for (int k = 0; k < j; ++k) o += DO * DI * (2 * (JS + k) + 1);
  return o;
}

// ============================================================================
// Init kernel: build the 19 Q tables (fp64) into ws[0..1225)
// ============================================================================
__device__ double dfact(int n) { double f = 1.0; for (int i = 2; i <= n; ++i) f *= (double)i; return f; }

__device__ double cgc(int l1, int m1, int l2, int m2, int l3, int m3) {
  if (m1 + m2 != m3) return 0.0;
  double pre = sqrt((2.0 * l3 + 1.0) * dfact(l3 + l1 - l2) * dfact(l3 - l1 + l2) *
                    dfact(l1 + l2 - l3) / dfact(l1 + l2 + l3 + 1));
  pre *= sqrt(dfact(l3 + m3) * dfact(l3 - m3) * dfact(l1 - m1) * dfact(l1 + m1) *
              dfact(l2 - m2) * dfact(l2 + m2));
  double s = 0.0;
  for (int k = 0; k <= l1 + l2 - l3; ++k) {
    int d1 = l1 + l2 - l3 - k, d2 = l1 - m1 - k, d3 = l2 + m2 - k;
    int d4 = l3 - l2 + m1 + k, d5 = l3 - l1 - m2 + k;
    if (d1 < 0 || d2 < 0 || d3 < 0 || d4 < 0 || d5 < 0) continue;
    double term = 1.0 / (dfact(k) * dfact(d1) * dfact(d2) * dfact(d3) * dfact(d4) * dfact(d5));
    s += (k & 1) ? -term : term;
  }
  return pre * s;
}

// nonzero entries of real-basis transform U(l) row a (complex); returns count
__device__ int urow(int l, int a, int* col, double* re, double* im) {
  const double RS = 0.7071067811865476;
  int m = a - l;
  if (m == 0) { col[0] = l; re[0] = 1.0; im[0] = 0.0; return 1; }
  if (m > 0) {
    double s = (m & 1) ? -1.0 : 1.0;
    col[0] = l + m; re[0] = s * RS; im[0] = 0.0;
    col[1] = l - m; re[1] = RS;     im[1] = 0.0;
    return 2;
  }
  int mm = -m;
  double s = (mm & 1) ? -1.0 : 1.0;
  col[0] = l + mm; re[0] = 0.0; im[0] = -s * RS;
  col[1] = l - mm; re[1] = 0.0; im[1] = RS;
  return 2;
}

__global__ __launch_bounds__(256) void init_q_kernel(float* __restrict__ ws) {
  constexpr int T_LO[19]  = {0,0,0, 1, 1,1,1, 1,1,1, 2, 2,2,2, 2,2,2,2,2};
  constexpr int T_LI[19]  = {0,1,2, 0, 1,1,1, 2,2,2, 0, 1,1,1, 2,2,2,2,2};
  constexpr int T_J [19]  = {0,1,2, 1, 0,1,2, 1,2,3, 2, 1,2,3, 0,1,2,3,4};
  constexpr int T_OFF[19] = {0,1,10,35,44,53,80,125,170,245,350,375,420,495,600,625,700,825,1000};

  const int t  = blockIdx.x;
  const int lo = T_LO[t], li = T_LI[t], J = T_J[t];
  const int d_o = 2 * lo + 1, d_i = 2 * li + 1, w = 2 * J + 1;
  const int size = d_o * d_i * w;
  const int e = threadIdx.x;

  double tre = 0.0, tim = 0.0;
  if (e < size) {
    int row = e / w, cc = e % w;
    int a = row / d_i, b = row % d_i;
    int co[2], ci[2], cj[2];
    double ro[2], io[2], ri[2], ii[2], rj[2], ij[2];
    int no = urow(lo, a,  co, ro, io);
    int ni = urow(li, b,  ci, ri, ii);
    int nj = urow(J,  cc, cj, rj, ij);
    for (int i0 = 0; i0 < no; ++i0)
      for (int i1 = 0; i1 < ni; ++i1)
        for (int i2 = 0; i2 < nj; ++i2) {
          double cg = cgc(li, ci[i1] - li, J, cj[i2] - J, lo, co[i0] - lo);
          if (cg == 0.0) continue;
          double ar = ro[i0], ai = io[i0];
          double br = ri[i1], bi = -ii[i1];   // conj
          double cr = rj[i2], cii = -ij[i2];  // conj
          double abr = ar * br - ai * bi, abi = ar * bi + ai * br;
          double pr = abr * cr - abi * cii, pi = abr * cii + abi * cr;
          tre += pr * cg; tim += pi * cg;
        }
  }
  // per-table choice: real part if sum|Re| >= sum|Im| (matches reference)
  __shared__ double sre[256], sim[256];
  sre[threadIdx.x] = fabs(tre);
  sim[threadIdx.x] = fabs(tim);
  __syncthreads();
  for (int s = 128; s > 0; s >>= 1) {
    if (threadIdx.x < s) { sre[threadIdx.x] += sre[threadIdx.x + s]; sim[threadIdx.x] += sim[threadIdx.x + s]; }
    __syncthreads();
  }
  if (e < size) ws[T_OFF[t] + e] = (float)((sre[0] >= sim[0]) ? tre : tim);
}

// ============================================================================
// Shared per-point preamble: windows (pre-scaled) + spherical harmonics
// ============================================================================
DEV void point_preamble(const float* __restrict__ diff, int n, int m,
                        float fv0, float* __restrict__ wv, float* __restrict__ Y) {
  const float* dp = diff + (((size_t)n << 8) + (size_t)m) * 3;
  const float dx = dp[0], dy = dp[1], dz = dp[2];
  const float r2 = dx * dx + dy * dy + dz * dz;
  const float r  = sqrtf(r2);
  const float rr = fmaxf(r, 1e-8f);
  const float inv = 1.0f / rr;
  const float x = dx * inv, y = dy * inv, z = dz * inv;

  {
    const float NORMC = 0.6649038006690546f;  // 1/(0.6*sqrt(2pi))
    const float RAD[4] = {0.5f, 1.0f, 1.5f, 2.0f};
#pragma unroll
    for (int k = 0; k < 4; ++k) {
      float tq = (r - RAD[k]) * (1.0f / 0.6f);
      wv[k] = expf(-0.5f * tq * tq) * (NORMC * fv0);
    }
  }
  {
    const float A1 = x,                 B1 = y * A1;
    const float A2 = x * A1 - y * B1,   B2 = x * B1 + y * A2;
    const float A3 = x * A2 - y * B2,   B3 = x * B2 + y * A3;
    const float A4 = x * A3 - y * B3,   B4 = x * B3 + y * A4;
    const float z2 = z * z;
    Y[0]  = 0.28209479177387814f;
    Y[1]  = 0.4886025119029199f * B1;
    Y[2]  = 0.4886025119029199f * z;
    Y[3]  = 0.4886025119029199f * A1;
    Y[4]  = 0.5462742152960396f * B2;
    Y[5]  = 1.0925484305920792f * z * B1;
    Y[6]  = 0.31539156525252005f * (3.0f * z2 - 1.0f);
    Y[7]  = 1.0925484305920792f * z * A1;
    Y[8]  = 0.5462742152960396f * A2;
    Y[9]  = 0.5900435899266435f * B3;
    Y[10] = 1.445305721320277f * z * B2;
    Y[11] = 0.4570457994644658f * (5.0f * z2 - 1.0f) * B1;
    Y[12] = 0.3731763325901154f * z * (5.0f * z2 - 3.0f);
    Y[13] = 0.4570457994644658f * (5.0f * z2 - 1.0f) * A1;
    Y[14] = 1.445305721320277f * z * A2;
    Y[15] = 0.5900435899266435f * A3;
    Y[16] = 0.6258357354491761f * B4;
    Y[17] = 1.7701307697799304f * z * B3;
    Y[18] = 0.47308734787878004f * (7.0f * z2 - 1.0f) * B2;
    Y[19] = 0.6690465435572892f * z * (7.0f * z2 - 3.0f) * B1;
    Y[20] = 0.10578554691520431f * ((35.0f * z2 - 30.0f) * z2 + 3.0f);
    Y[21] = 0.6690465435572892f * z * (7.0f * z2 - 3.0f) * A1;
    Y[22] = 0.47308734787878004f * (7.0f * z2 - 1.0f) * A2;
    Y[23] = 1.7701307697799304f * z * A3;
    Y[24] = 0.6258357354491761f * A4;
  }
}

// ============================================================================
// Light-path body (c-form, bit-identical to prior rounds). Paths 0,1,2,3,6.
// ============================================================================
template <int P>
DEV void do_path_light(const float* __restrict__ diff,
                       const float* __restrict__ w0g, const float* __restrict__ b0g,
                       const float* __restrict__ w1g, const float* __restrict__ b1g,
                       const float* __restrict__ Q, float* __restrict__ out,
                       int n, int m) {
  constexpr int LO = P / 3, LI = P % 3;
  constexpr int DO = 2 * LO + 1, DI = 2 * LI + 1;
  constexpr int JS = (LO > LI) ? (LO - LI) : (LI - LO);
  constexpr int NJ = 2 * ((LO < LI) ? LO : LI) + 1;
  constexpr int BEL = 4 * NJ;
  constexpr int ROFF = (LO == 0) ? 0 : ((LO == 1) ? 4 : 16);
  constexpr int COFF = (LI == 0) ? 0 : ((LI == 1) ? 4 : 16);
  constexpr int W0OFF = PW0[P];
  constexpr int QOFF  = PQOFF[P];
  const float FV0 = sqrtf((float)DO / (10.0f * (float)BEL * 9.0f));
  const float FV1 = sqrtf((float)DO / 360.0f);

  float wv[4], Y[25];
  point_preamble(diff, n, m, FV0, wv, Y);

  float c[10][NJ];
#pragma unroll
  for (int t = 0; t < 10; ++t) {
#pragma unroll
    for (int j = 0; j < NJ; ++j) {
      float acc = 0.0f;
#pragma unroll
      for (int rx = 0; rx < 4; ++rx)
        acc = fmaf(w0g[W0OFF + t * BEL + rx * NJ + j], wv[rx], acc);
      c[t][j] = acc;
    }
  }
  float b0v[10];
#pragma unroll
  for (int t = 0; t < 10; ++t) b0v[t] = b0g[10 * P + t];

  float* __restrict__ outn = out + ((size_t)n << 8);
  const float* __restrict__ w1p = w1g + 160 * P;
  const float* __restrict__ b1p = b1g + 16 * P;

#pragma unroll 1
  for (int a = 0; a < DO; ++a) {
#pragma unroll 1
    for (int b = 0; b < DI; ++b) {
      float K[NJ];
#pragma unroll
      for (int j = 0; j < NJ; ++j) {
        const int W = 2 * (JS + j) + 1;
        const int qbase = QOFF + qlocal(DO, DI, JS, j) + (a * DI + b) * W;
        float acc = 0.0f;
#pragma unroll
        for (int cc = 0; cc < 2 * (JS + j) + 1; ++cc)
          acc = fmaf(Q[qbase + cc], Y[YBASE[JS + j] + cc], acc);
        K[j] = acc;
      }
      float h[10];
#pragma unroll
      for (int t = 0; t < 10; ++t) {
        float acc = b0v[t];
#pragma unroll
        for (int j = 0; j < NJ; ++j) acc = fmaf(c[t][j], K[j], acc);
        h[t] = fmaxf(acc, 0.0f);
      }
#pragma unroll
      for (int u = 0; u < 4; ++u) {
        const int Rr = ROFF + u * DO + a;
#pragma unroll
        for (int v = 0; v < 4; ++v) {
          const int uv = u * 4 + v;
          float acc = 0.0f;
#pragma unroll
          for (int t = 0; t < 10; ++t)
            acc = fmaf(w1p[uv * 10 + t], h[t], acc);
          const float val = fmaf(acc, FV1, b1p[uv]);
          const int Cc = COFF + v * DI + b;
          float* __restrict__ op = outn + (((size_t)(Rr * 36 + Cc)) << 16);
          op[m] = val;
        }
      }
    }
  }
}

// ============================================================================
// Heavy-path body (Kt-form, low register pressure). Paths 4,5,7,8.
// One output row a per block. No c[][] array: radial dim folded per (a,b)
// as Kt[r][j] = wv[r]*K[j]; w0 consumed as SGPR operand in the h-FMAs.
// ============================================================================
template <int P>
DEV void do_path_heavy(const float* __restrict__ diff,
                       const float* __restrict__ w0g, const float* __restrict__ b0g,
                       const float* __restrict__ w1g, const float* __restrict__ b1g,
                       const float* __restrict__ Q, float* __restrict__ out,
                       int a, int n, int m) {
  constexpr int LO = P / 3, LI = P % 3;
  constexpr int DO = 2 * LO + 1, DI = 2 * LI + 1;
  constexpr int JS = (LO > LI) ? (LO - LI) : (LI - LO);
  constexpr int NJ = 2 * ((LO < LI) ? LO : LI) + 1;
  constexpr int BEL = 4 * NJ;
  constexpr int ROFF = (LO == 0) ? 0 : ((LO == 1) ? 4 : 16);
  constexpr int COFF = (LI == 0) ? 0 : ((LI == 1) ? 4 : 16);
  constexpr int W0OFF = PW0[P];
  constexpr int QOFF  = PQOFF[P];
  const float FV0 = sqrtf((float)DO / (10.0f * (float)BEL * 9.0f));
  const float FV1 = sqrtf((float)DO / 360.0f);

  float wv[4], Y[25];
  point_preamble(diff, n, m, FV0, wv, Y);

  float* __restrict__ outn = out + ((size_t)n << 8);
  const float* __restrict__ w1p = w1g + 160 * P;
  const float* __restrict__ b1p = b1g + 16 * P;
  const float* __restrict__ b0p = b0g + 10 * P;

#pragma unroll 1
  for (int b = 0; b < DI; ++b) {
    // K[j] = Q_row(a,b) . Y_J
    float K[NJ];
#pragma unroll
    for (int j = 0; j < NJ; ++j) {
      const int W = 2 * (JS + j) + 1;
      const int qbase = QOFF + qlocal(DO, DI, JS, j) + (a * DI + b) * W;
      float acc = 0.0f;
#pragma unroll
      for (int cc = 0; cc < 2 * (JS + j) + 1; ++cc)
        acc = fmaf(Q[qbase + cc], Y[YBASE[JS + j] + cc], acc);
      K[j] = acc;
    }
    // Kt[r][j] = wv[r]*K[j]  (replaces the 10xNJ c-array with 4xNJ)
    float Kt[4][NJ];
#pragma unroll
    for (int rx = 0; rx < 4; ++rx)
#pragma unroll
      for (int j = 0; j < NJ; ++j) Kt[rx][j] = wv[rx] * K[j];

    // h[t] = b0[t] + sum_{j,r} w0[t, r*NJ+j] * Kt[r][j]   (w0 via scalar path)
    float h[10];
#pragma unroll
    for (int t = 0; t < 10; ++t) {
      float acc = b0p[t];
#pragma unroll
      for (int j = 0; j < NJ; ++j)
#pragma unroll
        for (int rx = 0; rx < 4; ++rx)
          acc = fmaf(w0g[W0OFF + t * BEL + rx * NJ + j], Kt[rx][j], acc);
      h[t] = fmaxf(acc, 0.0f);
    }
    // layer 1 + coalesced stores
#pragma unroll
    for (int u = 0; u < 4; ++u) {
      const int Rr = ROFF + u * DO + a;
#pragma unroll
      for (int v = 0; v < 4; ++v) {
        const int uv = u * 4 + v;
        float acc = 0.0f;
#pragma unroll
        for (int t = 0; t < 10; ++t)
          acc = fmaf(w1p[uv * 10 + t], h[t], acc);
        const float val = fmaf(acc, FV1, b1p[uv]);
        const int Cc = COFF + v * DI + b;
        float* __restrict__ op = outn + (((size_t)(Rr * 36 + Cc)) << 16);
        op[m] = val;
      }
    }
  }
}

// ============================================================================
// Kernels
// ============================================================================
__global__ __launch_bounds__(256) void se3_light_kernel(
    const float* __restrict__ diff, const float* __restrict__ w0,
    const float* __restrict__ b0, const float* __restrict__ w1,
    const float* __restrict__ b1, const float* __restrict__ Q,
    float* __restrict__ out) {
  const int sel = blockIdx.x % 5;
  const int n   = blockIdx.x / 5;
  const int m   = threadIdx.x;
  switch (sel) {
    case 0: do_path_light<0>(diff, w0, b0, w1, b1, Q, out, n, m); break;
    case 1: do_path_light<1>(diff, w0, b0, w1, b1, Q, out, n, m); break;
    case 2: do_path_light<2>(diff, w0, b0, w1, b1, Q, out, n, m); break;
    case 3: do_path_light<3>(diff, w0, b0, w1, b1, Q, out, n, m); break;
    case 4: do_path_light<6>(diff, w0, b0, w1, b1, Q, out, n, m); break;
  }
}

template <int P>
__global__ __launch_bounds__(256, 1) void se3_heavy_kernel(
    const float* __restrict__ diff, const float* __restrict__ w0,
    const float* __restrict__ b0, const float* __restrict__ w1,
    const float* __restrict__ b1, const float* __restrict__ Q,
    float* __restrict__ out) {
  constexpr int DO = 2 * (P / 3) + 1;
  const int a = blockIdx.x % DO;
  const int n = blockIdx.x / DO;
  do_path_heavy<P>(diff, w0, b0, w1, b1, Q, out, a, n, threadIdx.x);
}

extern "C" void kernel_launch(void* const* d_in, const int* in_sizes, int n_in,
                              void* d_out, int out_size, void* d_ws, size_t ws_size,
                              hipStream_t stream) {
  const float* diff = (const float*)d_in[0];
  const float* w0   = (const float*)d_in[1];
  const float* b0   = (const float*)d_in[2];
  const float* w1   = (const float*)d_in[3];
  const float* b1   = (const float*)d_in[4];
  float* out = (float*)d_out;
  float* qws = (float*)d_ws;  // needs 1225 floats; rebuilt every call (ws is re-poisoned)

  init_q_kernel<<<dim3(19), dim3(256), 0, stream>>>(qws);
  // heavy first (largest write volume), then light
  se3_heavy_kernel<8><<<dim3(5 * 256), dim3(256), 0, stream>>>(diff, w0, b0, w1, b1, qws, out);
  se3_heavy_kernel<7><<<dim3(5 * 256), dim3(256), 0, stream>>>(diff, w0, b0, w1, b1, qws, out);
  se3_heavy_kernel<5><<<dim3(3 * 256), dim3(256), 0, stream>>>(diff, w0, b0, w1, b1, qws, out);
  se3_heavy_kernel<4><<<dim3(3 * 256), dim3(256), 0, stream>>>(diff, w0, b0, w1, b1, qws, out);
  se3_light_kernel<<<dim3(5 * 256), dim3(256), 0, stream>>>(diff, w0, b0, w1, b1, qws, out);
}

// Round 7
// 448.063 us; speedup vs baseline: 1.4956x; 1.4956x over previous
//
#include <hip/hip_runtime.h>

// ============================================================================
// SE3 two-layer point kernel, MI355X (gfx950)
// Output: (36,36,256,256) fp32, ~340 MB -> HBM-write floor ~52us (+212us
// harness re-poison fill we cannot control).
//
// R7 = R5 RESUBMIT #2. Rounds 5 and 6 both failed with "MI355X container
// failed twice" -- an acquisition-level error (no timing/compile/absmax in
// the result JSON), which occurs before the kernel is compiled or run. The
// source cannot cause it; device code is structurally identical to the
// baseline mega-kernel that passed in rounds 0-2 (9 inlined path bodies in
// one switch). Resubmitting unchanged to preserve the fusion A/B.
//
// R5 design: REVERT R4's Kt-form (regressed 440->670: it rebuilt ~200 w0
// scalar loads inside the b-loop -> exposed lgkmcnt serialization). Back to
// R3's c-form bodies (best: 440us), but merged into a SINGLE LAUNCH:
//   flat work space of 21 kinds x 256 n-rows, kind = bid % 21:
//     kinds 0-4  : path 8, a = kind      (heavy, one output row per block)
//     kinds 5-9  : path 7, a = kind-5
//     kinds 10-12: path 5, a = kind-10
//     kinds 13-15: path 4, a = kind-13
//     kinds 16-20: light paths 0,1,2,3,6 (all a-rows in one block)
//   Removes 4 stream-serialization barriers of R3 (each paid ramp+tail with
//   a 3x path-duration skew and no cross-launch backfill) and restores
//   counter visibility (one main kernel row in rocprof).
// Per-element arithmetic identical to R3 -> absmax unchanged.
// ============================================================================

#define DEV __device__ __forceinline__

// ----- compile-time path metadata: path p = lo*3 + li ------------------------
constexpr int PW0[9]   = {0,40,80,120,160,280,400,440,560};   // weight_0 offsets
constexpr int PQOFF[9] = {0,1,10,35,44,125,350,375,600};      // Q table base (floats)
constexpr int YBASE[5] = {0,1,4,9,16};                        // Y row offset per J

__host__ __device__ constexpr int qlocal(int DO, int DI, int JS, int j) {
  int o = 0;
  for (int k = 0; k < j; ++k) o += DO * DI * (2 * (JS + k) + 1);
  return o;
}

// ============================================================================
// Init kernel: build the 19 Q tables (fp64) into ws[0..1225)
// ============================================================================
__device__ double dfact(int n) { double f = 1.0; for (int i = 2; i <= n; ++i) f *= (double)i; return f; }

__device__ double cgc(int l1, int m1, int l2, int m2, int l3, int m3) {
  if (m1 + m2 != m3) return 0.0;
  double pre = sqrt((2.0 * l3 + 1.0) * dfact(l3 + l1 - l2) * dfact(l3 - l1 + l2) *
                    dfact(l1 + l2 - l3) / dfact(l1 + l2 + l3 + 1));
  pre *= sqrt(dfact(l3 + m3) * dfact(l3 - m3) * dfact(l1 - m1) * dfact(l1 + m1) *
              dfact(l2 - m2) * dfact(l2 + m2));
  double s = 0.0;
  for (int k = 0; k <= l1 + l2 - l3; ++k) {
    int d1 = l1 + l2 - l3 - k, d2 = l1 - m1 - k, d3 = l2 + m2 - k;
    int d4 = l3 - l2 + m1 + k, d5 = l3 - l1 - m2 + k;
    if (d1 < 0 || d2 < 0 || d3 < 0 || d4 < 0 || d5 < 0) continue;
    double term = 1.0 / (dfact(k) * dfact(d1) * dfact(d2) * dfact(d3) * dfact(d4) * dfact(d5));
    s += (k & 1) ? -term : term;
  }
  return pre * s;
}

// nonzero entries of real-basis transform U(l) row a (complex); returns count
__device__ int urow(int l, int a, int* col, double* re, double* im) {
  const double RS = 0.7071067811865476;
  int m = a - l;
  if (m == 0) { col[0] = l; re[0] = 1.0; im[0] = 0.0; return 1; }
  if (m > 0) {
    double s = (m & 1) ? -1.0 : 1.0;
    col[0] = l + m; re[0] = s * RS; im[0] = 0.0;
    col[1] = l - m; re[1] = RS;     im[1] = 0.0;
    return 2;
  }
  int mm = -m;
  double s = (mm & 1) ? -1.0 : 1.0;
  col[0] = l + mm; re[0] = 0.0; im[0] = -s * RS;
  col[1] = l - mm; re[1] = 0.0; im[1] = RS;
  return 2;
}

__global__ __launch_bounds__(256) void init_q_kernel(float* __restrict__ ws) {
  constexpr int T_LO[19]  = {0,0,0, 1, 1,1,1, 1,1,1, 2, 2,2,2, 2,2,2,2,2};
  constexpr int T_LI[19]  = {0,1,2, 0, 1,1,1, 2,2,2, 0, 1,1,1, 2,2,2,2,2};
  constexpr int T_J [19]  = {0,1,2, 1, 0,1,2, 1,2,3, 2, 1,2,3, 0,1,2,3,4};
  constexpr int T_OFF[19] = {0,1,10,35,44,53,80,125,170,245,350,375,420,495,600,625,700,825,1000};

  const int t  = blockIdx.x;
  const int lo = T_LO[t], li = T_LI[t], J = T_J[t];
  const int d_o = 2 * lo + 1, d_i = 2 * li + 1, w = 2 * J + 1;
  const int size = d_o * d_i * w;
  const int e = threadIdx.x;

  double tre = 0.0, tim = 0.0;
  if (e < size) {
    int row = e / w, cc = e % w;
    int a = row / d_i, b = row % d_i;
    int co[2], ci[2], cj[2];
    double ro[2], io[2], ri[2], ii[2], rj[2], ij[2];
    int no = urow(lo, a,  co, ro, io);
    int ni = urow(li, b,  ci, ri, ii);
    int nj = urow(J,  cc, cj, rj, ij);
    for (int i0 = 0; i0 < no; ++i0)
      for (int i1 = 0; i1 < ni; ++i1)
        for (int i2 = 0; i2 < nj; ++i2) {
          double cg = cgc(li, ci[i1] - li, J, cj[i2] - J, lo, co[i0] - lo);
          if (cg == 0.0) continue;
          double ar = ro[i0], ai = io[i0];
          double br = ri[i1], bi = -ii[i1];   // conj
          double cr = rj[i2], cii = -ij[i2];  // conj
          double abr = ar * br - ai * bi, abi = ar * bi + ai * br;
          double pr = abr * cr - abi * cii, pi = abr * cii + abi * cr;
          tre += pr * cg; tim += pi * cg;
        }
  }
  // per-table choice: real part if sum|Re| >= sum|Im| (matches reference)
  __shared__ double sre[256], sim[256];
  sre[threadIdx.x] = fabs(tre);
  sim[threadIdx.x] = fabs(tim);
  __syncthreads();
  for (int s = 128; s > 0; s >>= 1) {
    if (threadIdx.x < s) { sre[threadIdx.x] += sre[threadIdx.x + s]; sim[threadIdx.x] += sim[threadIdx.x + s]; }
    __syncthreads();
  }
  if (e < size) ws[T_OFF[t] + e] = (float)((sre[0] >= sim[0]) ? tre : tim);
}

// ============================================================================
// Path body (c-form, identical arithmetic to R3): rows a in [a0, a0+na)
// ============================================================================
template <int P>
DEV void do_path(const float* __restrict__ diff,
                 const float* __restrict__ w0g, const float* __restrict__ b0g,
                 const float* __restrict__ w1g, const float* __restrict__ b1g,
                 const float* __restrict__ Q, float* __restrict__ out,
                 int a0, int na, int n, int m) {
  constexpr int LO = P / 3, LI = P % 3;
  constexpr int DO = 2 * LO + 1, DI = 2 * LI + 1;
  constexpr int JS = (LO > LI) ? (LO - LI) : (LI - LO);   // J start
  constexpr int NJ = 2 * ((LO < LI) ? LO : LI) + 1;        // number of J's
  constexpr int BEL = 4 * NJ;                              // b_el = radii * nJ
  constexpr int ROFF = (LO == 0) ? 0 : ((LO == 1) ? 4 : 16);
  constexpr int COFF = (LI == 0) ? 0 : ((LI == 1) ? 4 : 16);
  constexpr int W0OFF = PW0[P];
  constexpr int QOFF  = PQOFF[P];
  const float FV0 = sqrtf((float)DO / (10.0f * (float)BEL * 9.0f));
  const float FV1 = sqrtf((float)DO / 360.0f);

  const float* dp = diff + (((size_t)n << 8) + (size_t)m) * 3;
  const float dx = dp[0], dy = dp[1], dz = dp[2];
  const float r2 = dx * dx + dy * dy + dz * dz;
  const float r  = sqrtf(r2);
  const float rr = fmaxf(r, 1e-8f);
  const float inv = 1.0f / rr;
  const float x = dx * inv, y = dy * inv, z = dz * inv;

  // Gaussian windows, pre-scaled by fv0 (folds layer-0 scale)
  float wv[4];
  {
    const float NORMC = 0.6649038006690546f;  // 1/(0.6*sqrt(2pi))
    const float RAD[4] = {0.5f, 1.0f, 1.5f, 2.0f};
#pragma unroll
    for (int k = 0; k < 4; ++k) {
      float tq = (r - RAD[k]) * (1.0f / 0.6f);
      wv[k] = expf(-0.5f * tq * tq) * (NORMC * FV0);
    }
  }

  // real spherical harmonics, replicating reference recurrences EXACTLY.
  float Y[25];
  {
    const float A1 = x,                 B1 = y * A1;
    const float A2 = x * A1 - y * B1,   B2 = x * B1 + y * A2;
    const float A3 = x * A2 - y * B2,   B3 = x * B2 + y * A3;
    const float A4 = x * A3 - y * B3,   B4 = x * B3 + y * A4;
    const float z2 = z * z;
    Y[0]  = 0.28209479177387814f;
    Y[1]  = 0.4886025119029199f * B1;
    Y[2]  = 0.4886025119029199f * z;
    Y[3]  = 0.4886025119029199f * A1;
    Y[4]  = 0.5462742152960396f * B2;
    Y[5]  = 1.0925484305920792f * z * B1;
    Y[6]  = 0.31539156525252005f * (3.0f * z2 - 1.0f);
    Y[7]  = 1.0925484305920792f * z * A1;
    Y[8]  = 0.5462742152960396f * A2;
    Y[9]  = 0.5900435899266435f * B3;
    Y[10] = 1.445305721320277f * z * B2;
    Y[11] = 0.4570457994644658f * (5.0f * z2 - 1.0f) * B1;
    Y[12] = 0.3731763325901154f * z * (5.0f * z2 - 3.0f);
    Y[13] = 0.4570457994644658f * (5.0f * z2 - 1.0f) * A1;
    Y[14] = 1.445305721320277f * z * A2;
    Y[15] = 0.5900435899266435f * A3;
    Y[16] = 0.6258357354491761f * B4;
    Y[17] = 1.7701307697799304f * z * B3;
    Y[18] = 0.47308734787878004f * (7.0f * z2 - 1.0f) * B2;
    Y[19] = 0.6690465435572892f * z * (7.0f * z2 - 3.0f) * B1;
    Y[20] = 0.10578554691520431f * ((35.0f * z2 - 30.0f) * z2 + 3.0f);
    Y[21] = 0.6690465435572892f * z * (7.0f * z2 - 3.0f) * A1;
    Y[22] = 0.47308734787878004f * (7.0f * z2 - 1.0f) * A2;
    Y[23] = 1.7701307697799304f * z * A3;
    Y[24] = 0.6258357354491761f * A4;
  }

  // collapse radial dim: c[t][j] = sum_r w0[t, r*NJ+j] * win_r * fv0
  float c[10][NJ];
#pragma unroll
  for (int t = 0; t < 10; ++t) {
#pragma unroll
    for (int j = 0; j < NJ; ++j) {
      float acc = 0.0f;
#pragma unroll
      for (int rx = 0; rx < 4; ++rx)
        acc = fmaf(w0g[W0OFF + t * BEL + rx * NJ + j], wv[rx], acc);
      c[t][j] = acc;
    }
  }
  float b0v[10];
#pragma unroll
  for (int t = 0; t < 10; ++t) b0v[t] = b0g[10 * P + t];

  float* __restrict__ outn = out + ((size_t)n << 8);
  const float* __restrict__ w1p = w1g + 160 * P;
  const float* __restrict__ b1p = b1g + 16 * P;

#pragma unroll 1
  for (int ai = 0; ai < na; ++ai) {
    const int a = a0 + ai;
#pragma unroll 1
    for (int b = 0; b < DI; ++b) {
      // K[j] = Q_row(a,b) . Y_J
      float K[NJ];
#pragma unroll
      for (int j = 0; j < NJ; ++j) {
        const int W = 2 * (JS + j) + 1;
        const int qbase = QOFF + qlocal(DO, DI, JS, j) + (a * DI + b) * W;
        float acc = 0.0f;
#pragma unroll
        for (int cc = 0; cc < 2 * (JS + j) + 1; ++cc)
          acc = fmaf(Q[qbase + cc], Y[YBASE[JS + j] + cc], acc);
        K[j] = acc;
      }
      // layer 0
      float h[10];
#pragma unroll
      for (int t = 0; t < 10; ++t) {
        float acc = b0v[t];
#pragma unroll
        for (int j = 0; j < NJ; ++j) acc = fmaf(c[t][j], K[j], acc);
        h[t] = fmaxf(acc, 0.0f);
      }
      // layer 1 + scatter (coalesced along m)
#pragma unroll
      for (int u = 0; u < 4; ++u) {
        const int Rr = ROFF + u * DO + a;
#pragma unroll
        for (int v = 0; v < 4; ++v) {
          const int uv = u * 4 + v;
          float acc = 0.0f;
#pragma unroll
          for (int t = 0; t < 10; ++t)
            acc = fmaf(w1p[uv * 10 + t], h[t], acc);
          const float val = fmaf(acc, FV1, b1p[uv]);
          const int Cc = COFF + v * DI + b;
          float* __restrict__ op = outn + (((size_t)(Rr * 36 + Cc)) << 16);
          op[m] = val;
        }
      }
    }
  }
}

// ============================================================================
// Single fused launch: 21 kinds x 256 n-rows, kinds interleaved across CUs.
//   kinds 0-4  : path 8, a=kind    kinds 5-9  : path 7, a=kind-5
//   kinds 10-12: path 5, a=kind-10 kinds 13-15: path 4, a=kind-13
//   kind 16-20 : light paths 0,1,2,3,6 (all rows)
// ============================================================================
__global__ __launch_bounds__(256) void se3_all_kernel(
    const float* __restrict__ diff, const float* __restrict__ w0,
    const float* __restrict__ b0, const float* __restrict__ w1,
    const float* __restrict__ b1, const float* __restrict__ Q,
    float* __restrict__ out) {
  const int kind = blockIdx.x % 21;
  const int n    = blockIdx.x / 21;
  const int m    = threadIdx.x;
  switch (kind) {
    case 0: case 1: case 2: case 3: case 4:
      do_path<8>(diff, w0, b0, w1, b1, Q, out, kind, 1, n, m); break;
    case 5: case 6: case 7: case 8: case 9:
      do_path<7>(diff, w0, b0, w1, b1, Q, out, kind - 5, 1, n, m); break;
    case 10: case 11: case 12:
      do_path<5>(diff, w0, b0, w1, b1, Q, out, kind - 10, 1, n, m); break;
    case 13: case 14: case 15:
      do_path<4>(diff, w0, b0, w1, b1, Q, out, kind - 13, 1, n, m); break;
    case 16: do_path<0>(diff, w0, b0, w1, b1, Q, out, 0, 1, n, m); break;
    case 17: do_path<1>(diff, w0, b0, w1, b1, Q, out, 0, 1, n, m); break;
    case 18: do_path<2>(diff, w0, b0, w1, b1, Q, out, 0, 1, n, m); break;
    case 19: do_path<3>(diff, w0, b0, w1, b1, Q, out, 0, 3, n, m); break;
    case 20: do_path<6>(diff, w0, b0, w1, b1, Q, out, 0, 5, n, m); break;
  }
}

extern "C" void kernel_launch(void* const* d_in, const int* in_sizes, int n_in,
                              void* d_out, int out_size, void* d_ws, size_t ws_size,
                              hipStream_t stream) {
  const float* diff = (const float*)d_in[0];
  const float* w0   = (const float*)d_in[1];
  const float* b0   = (const float*)d_in[2];
  const float* w1   = (const float*)d_in[3];
  const float* b1   = (const float*)d_in[4];
  float* out = (float*)d_out;
  float* qws = (float*)d_ws;  // needs 1225 floats; rebuilt every call (ws is re-poisoned)

  init_q_kernel<<<dim3(19), dim3(256), 0, stream>>>(qws);
  se3_all_kernel<<<dim3(21 * 256), dim3(256), 0, stream>>>(diff, w0, b0, w1, b1, qws, out);
}

// Round 8
// 387.574 us; speedup vs baseline: 1.7290x; 1.1561x over previous
//
#include <hip/hip_runtime.h>

// ============================================================================
// SE3 two-layer point kernel, MI355X (gfx950)
// Output: (36,36,256,256) fp32, ~340 MB -> HBM-write floor ~54us (+~220us
// harness re-poison fill we cannot control).
//
// R8: FINE-GRAINED (path,a,b) DECOMPOSITION + STAGED BASIS.
//   Evidence: fusion/launch structure neutral (R3 440 vs R7 448); mega vs
//   split preamble count neutral; all compiler-forcing attempts failed with
//   VGPR pinned at 64 and ~4-8x dynamic VALU. Last standing theory: the
//   per-thread live set (Y[25]+c[50]+...) across the 25-iter (a,b) loop is
//   what the backend refuses to keep resident, paying per-iteration
//   (remat/AGPR/scratch-in-L2, invisible to HBM counters, occupancy ~25%).
//   Never attacked directly: SHRINK the per-block problem.
//   - Stage 1: per point compute windows(4)+Y(25) once -> ws planes
//     (29 x 65536 floats = 7.6 MB, L2-resident). ws_size guard + R7 fallback.
//   - Stage 2: 81 kinds x 256 n-rows; kind = one (path, a, b). Each block:
//     load ~29 staged floats, K[NJ] dot, h[10] (w0 folded per-j, no c array),
//     16 outputs. Peak live ~50 VGPR -> fits 64 BY CONSTRUCTION. Uniform
//     small blocks (no tail skew), 20736 blocks TLP, weights s_loaded once.
//   Cost: ~1.6x FLOPs vs fused form (~24us ideal VALU) -- cheap insurance.
//   Numerics: layer-0 sum reassociation only (R4 showed this passes).
// ============================================================================

#define DEV __device__ __forceinline__

// ----- compile-time path metadata: path p = lo*3 + li ------------------------
constexpr int PW0[9]   = {0,40,80,120,160,280,400,440,560};   // weight_0 offsets
constexpr int PQOFF[9] = {0,1,10,35,44,125,350,375,600};      // Q table base (floats)
constexpr int YBASE[5] = {0,1,4,9,16};                        // Y row offset per J

__host__ __device__ constexpr int qlocal(int DO, int DI, int JS, int j) {
  int o = 0;
  for (int k = 0; k < j; ++k) o += DO * DI * (2 * (JS + k) + 1);
  return o;
}

// ws layout: [0..1225) Q tables; [2048 ..) staged planes, stride 65536 floats:
//   planes 0-3: windows (exp * NORMC, unscaled by fv0); planes 4-28: Y[0..25)
constexpr int WSY = 2048;
constexpr int PLANE = 65536;

// ============================================================================
// Init kernel: build the 19 Q tables (fp64) into ws[0..1225)
// ============================================================================
__device__ double dfact(int n) { double f = 1.0; for (int i = 2; i <= n; ++i) f *= (double)i; return f; }

__device__ double cgc(int l1, int m1, int l2, int m2, int l3, int m3) {
  if (m1 + m2 != m3) return 0.0;
  double pre = sqrt((2.0 * l3 + 1.0) * dfact(l3 + l1 - l2) * dfact(l3 - l1 + l2) *
                    dfact(l1 + l2 - l3) / dfact(l1 + l2 + l3 + 1));
  pre *= sqrt(dfact(l3 + m3) * dfact(l3 - m3) * dfact(l1 - m1) * dfact(l1 + m1) *
              dfact(l2 - m2) * dfact(l2 + m2));
  double s = 0.0;
  for (int k = 0; k <= l1 + l2 - l3; ++k) {
    int d1 = l1 + l2 - l3 - k, d2 = l1 - m1 - k, d3 = l2 + m2 - k;
    int d4 = l3 - l2 + m1 + k, d5 = l3 - l1 - m2 + k;
    if (d1 < 0 || d2 < 0 || d3 < 0 || d4 < 0 || d5 < 0) continue;
    double term = 1.0 / (dfact(k) * dfact(d1) * dfact(d2) * dfact(d3) * dfact(d4) * dfact(d5));
    s += (k & 1) ? -term : term;
  }
  return pre * s;
}

__device__ int urow(int l, int a, int* col, double* re, double* im) {
  const double RS = 0.7071067811865476;
  int m = a - l;
  if (m == 0) { col[0] = l; re[0] = 1.0; im[0] = 0.0; return 1; }
  if (m > 0) {
    double s = (m & 1) ? -1.0 : 1.0;
    col[0] = l + m; re[0] = s * RS; im[0] = 0.0;
    col[1] = l - m; re[1] = RS;     im[1] = 0.0;
    return 2;
  }
  int mm = -m;
  double s = (mm & 1) ? -1.0 : 1.0;
  col[0] = l + mm; re[0] = 0.0; im[0] = -s * RS;
  col[1] = l - mm; re[1] = 0.0; im[1] = RS;
  return 2;
}

__global__ __launch_bounds__(256) void init_q_kernel(float* __restrict__ ws) {
  constexpr int T_LO[19]  = {0,0,0, 1, 1,1,1, 1,1,1, 2, 2,2,2, 2,2,2,2,2};
  constexpr int T_LI[19]  = {0,1,2, 0, 1,1,1, 2,2,2, 0, 1,1,1, 2,2,2,2,2};
  constexpr int T_J [19]  = {0,1,2, 1, 0,1,2, 1,2,3, 2, 1,2,3, 0,1,2,3,4};
  constexpr int T_OFF[19] = {0,1,10,35,44,53,80,125,170,245,350,375,420,495,600,625,700,825,1000};

  const int t  = blockIdx.x;
  const int lo = T_LO[t], li = T_LI[t], J = T_J[t];
  const int d_o = 2 * lo + 1, d_i = 2 * li + 1, w = 2 * J + 1;
  const int size = d_o * d_i * w;
  const int e = threadIdx.x;

  double tre = 0.0, tim = 0.0;
  if (e < size) {
    int row = e / w, cc = e % w;
    int a = row / d_i, b = row % d_i;
    int co[2], ci[2], cj[2];
    double ro[2], io[2], ri[2], ii[2], rj[2], ij[2];
    int no = urow(lo, a,  co, ro, io);
    int ni = urow(li, b,  ci, ri, ii);
    int nj = urow(J,  cc, cj, rj, ij);
    for (int i0 = 0; i0 < no; ++i0)
      for (int i1 = 0; i1 < ni; ++i1)
        for (int i2 = 0; i2 < nj; ++i2) {
          double cg = cgc(li, ci[i1] - li, J, cj[i2] - J, lo, co[i0] - lo);
          if (cg == 0.0) continue;
          double ar = ro[i0], ai = io[i0];
          double br = ri[i1], bi = -ii[i1];   // conj
          double cr = rj[i2], cii = -ij[i2];  // conj
          double abr = ar * br - ai * bi, abi = ar * bi + ai * br;
          double pr = abr * cr - abi * cii, pi = abr * cii + abi * cr;
          tre += pr * cg; tim += pi * cg;
        }
  }
  __shared__ double sre[256], sim[256];
  sre[threadIdx.x] = fabs(tre);
  sim[threadIdx.x] = fabs(tim);
  __syncthreads();
  for (int s = 128; s > 0; s >>= 1) {
    if (threadIdx.x < s) { sre[threadIdx.x] += sre[threadIdx.x + s]; sim[threadIdx.x] += sim[threadIdx.x + s]; }
    __syncthreads();
  }
  if (e < size) ws[T_OFF[t] + e] = (float)((sre[0] >= sim[0]) ? tre : tim);
}

// ============================================================================
// Stage 1: per-point windows (exp*NORMC) + Y[25] -> ws planes (SoA, coalesced)
// ============================================================================
__global__ __launch_bounds__(256) void se3_stage1(const float* __restrict__ diff,
                                                  float* __restrict__ ws) {
  const int n = blockIdx.x, m = threadIdx.x;
  const int nm = (n << 8) | m;
  const float* dp = diff + (size_t)nm * 3;
  const float dx = dp[0], dy = dp[1], dz = dp[2];
  const float r2 = dx * dx + dy * dy + dz * dz;
  const float r  = sqrtf(r2);
  const float rr = fmaxf(r, 1e-8f);
  const float inv = 1.0f / rr;
  const float x = dx * inv, y = dy * inv, z = dz * inv;

  float* base = ws + WSY + nm;

  {
    const float NORMC = 0.6649038006690546f;  // 1/(0.6*sqrt(2pi))
    const float RAD[4] = {0.5f, 1.0f, 1.5f, 2.0f};
#pragma unroll
    for (int k = 0; k < 4; ++k) {
      float tq = (r - RAD[k]) * (1.0f / 0.6f);
      base[(size_t)k * PLANE] = expf(-0.5f * tq * tq) * NORMC;
    }
  }
  {
    const float A1 = x,                 B1 = y * A1;
    const float A2 = x * A1 - y * B1,   B2 = x * B1 + y * A2;
    const float A3 = x * A2 - y * B2,   B3 = x * B2 + y * A3;
    const float A4 = x * A3 - y * B3,   B4 = x * B3 + y * A4;
    const float z2 = z * z;
    float Y[25];
    Y[0]  = 0.28209479177387814f;
    Y[1]  = 0.4886025119029199f * B1;
    Y[2]  = 0.4886025119029199f * z;
    Y[3]  = 0.4886025119029199f * A1;
    Y[4]  = 0.5462742152960396f * B2;
    Y[5]  = 1.0925484305920792f * z * B1;
    Y[6]  = 0.31539156525252005f * (3.0f * z2 - 1.0f);
    Y[7]  = 1.0925484305920792f * z * A1;
    Y[8]  = 0.5462742152960396f * A2;
    Y[9]  = 0.5900435899266435f * B3;
    Y[10] = 1.445305721320277f * z * B2;
    Y[11] = 0.4570457994644658f * (5.0f * z2 - 1.0f) * B1;
    Y[12] = 0.3731763325901154f * z * (5.0f * z2 - 3.0f);
    Y[13] = 0.4570457994644658f * (5.0f * z2 - 1.0f) * A1;
    Y[14] = 1.445305721320277f * z * A2;
    Y[15] = 0.5900435899266435f * A3;
    Y[16] = 0.6258357354491761f * B4;
    Y[17] = 1.7701307697799304f * z * B3;
    Y[18] = 0.47308734787878004f * (7.0f * z2 - 1.0f) * B2;
    Y[19] = 0.6690465435572892f * z * (7.0f * z2 - 3.0f) * B1;
    Y[20] = 0.10578554691520431f * ((35.0f * z2 - 30.0f) * z2 + 3.0f);
    Y[21] = 0.6690465435572892f * z * (7.0f * z2 - 3.0f) * A1;
    Y[22] = 0.47308734787878004f * (7.0f * z2 - 1.0f) * A2;
    Y[23] = 1.7701307697799304f * z * A3;
    Y[24] = 0.6258357354491761f * A4;
#pragma unroll
    for (int i = 0; i < 25; ++i) base[(size_t)(4 + i) * PLANE] = Y[i];
  }
}

// ============================================================================
// Stage 2 body: ONE (path, a, b) pair for point (n, m). Tiny live set.
// ============================================================================
template <int P>
DEV void do_pair(const float* __restrict__ w0g, const float* __restrict__ b0g,
                 const float* __restrict__ w1g, const float* __restrict__ b1g,
                 const float* __restrict__ ws, float* __restrict__ out,
                 int ab, int n, int m) {
  constexpr int LO = P / 3, LI = P % 3;
  constexpr int DO = 2 * LO + 1, DI = 2 * LI + 1;
  constexpr int JS = (LO > LI) ? (LO - LI) : (LI - LO);
  constexpr int NJ = 2 * ((LO < LI) ? LO : LI) + 1;
  constexpr int BEL = 4 * NJ;
  constexpr int ROFF = (LO == 0) ? 0 : ((LO == 1) ? 4 : 16);
  constexpr int COFF = (LI == 0) ? 0 : ((LI == 1) ? 4 : 16);
  constexpr int W0OFF = PW0[P];
  constexpr int QOFF  = PQOFF[P];
  constexpr int YLO = YBASE[JS];                                   // first Y row used
  constexpr int YHI = YBASE[JS + NJ - 1] + 2 * (JS + NJ - 1) + 1;  // one past last
  const float FV0 = sqrtf((float)DO / (10.0f * (float)BEL * 9.0f));
  const float FV1 = sqrtf((float)DO / 360.0f);

  const int nm = (n << 8) | m;
  const float* __restrict__ sb = ws + WSY + nm;

  // staged loads: windows (fold fv0) + needed Y rows. Coalesced along m.
  float wvs[4];
#pragma unroll
  for (int k = 0; k < 4; ++k) wvs[k] = sb[(size_t)k * PLANE] * FV0;
  float Yv[YHI - YLO];
#pragma unroll
  for (int i = 0; i < YHI - YLO; ++i) Yv[i] = sb[(size_t)(4 + YLO + i) * PLANE];

  const int a = ab / DI, b = ab - a * DI;

  // K[j] = Q_row(a,b) . Y_J
  const float* __restrict__ Q = ws;
  float K[NJ];
#pragma unroll
  for (int j = 0; j < NJ; ++j) {
    const int W = 2 * (JS + j) + 1;
    const int qbase = QOFF + qlocal(DO, DI, JS, j) + ab * W;
    float acc = 0.0f;
#pragma unroll
    for (int cc = 0; cc < 2 * (JS + j) + 1; ++cc)
      acc = fmaf(Q[qbase + cc], Yv[YBASE[JS + j] - YLO + cc], acc);
    K[j] = acc;
  }

  // layer 0: h[t] = b0[t] + sum_j (sum_r w0[t,r,j]*wvs[r]) * K[j]
  const float* __restrict__ b0p = b0g + 10 * P;
  float h[10];
#pragma unroll
  for (int t = 0; t < 10; ++t) {
    float acc = b0p[t];
#pragma unroll
    for (int j = 0; j < NJ; ++j) {
      float cj = w0g[W0OFF + t * BEL + 0 * NJ + j] * wvs[0];
#pragma unroll
      for (int rx = 1; rx < 4; ++rx)
        cj = fmaf(w0g[W0OFF + t * BEL + rx * NJ + j], wvs[rx], cj);
      acc = fmaf(cj, K[j], acc);
    }
    h[t] = fmaxf(acc, 0.0f);
  }

  // layer 1 + 16 coalesced stores
  const float* __restrict__ w1p = w1g + 160 * P;
  const float* __restrict__ b1p = b1g + 16 * P;
  float* __restrict__ outn = out + ((size_t)n << 8);
#pragma unroll
  for (int u = 0; u < 4; ++u) {
    const int Rr = ROFF + u * DO + a;
#pragma unroll
    for (int v = 0; v < 4; ++v) {
      const int uv = u * 4 + v;
      float acc = 0.0f;
#pragma unroll
      for (int t = 0; t < 10; ++t)
        acc = fmaf(w1p[uv * 10 + t], h[t], acc);
      const float val = fmaf(acc, FV1, b1p[uv]);
      const int Cc = COFF + v * DI + b;
      float* __restrict__ op = outn + (((size_t)(Rr * 36 + Cc)) << 16);
      op[m] = val;
    }
  }
}

// 81 kinds: p0:[0,1) p1:[1,4) p2:[4,9) p3:[9,12) p4:[12,21) p5:[21,36)
//           p6:[36,41) p7:[41,56) p8:[56,81)
__global__ __launch_bounds__(256) void se3_stage2(
    const float* __restrict__ w0, const float* __restrict__ b0,
    const float* __restrict__ w1, const float* __restrict__ b1,
    const float* __restrict__ ws, float* __restrict__ out) {
  const int kind = blockIdx.x % 81;
  const int n    = blockIdx.x / 81;
  const int m    = threadIdx.x;
  if      (kind < 1)  do_pair<0>(w0, b0, w1, b1, ws, out, kind,      n, m);
  else if (kind < 4)  do_pair<1>(w0, b0, w1, b1, ws, out, kind - 1,  n, m);
  else if (kind < 9)  do_pair<2>(w0, b0, w1, b1, ws, out, kind - 4,  n, m);
  else if (kind < 12) do_pair<3>(w0, b0, w1, b1, ws, out, kind - 9,  n, m);
  else if (kind < 21) do_pair<4>(w0, b0, w1, b1, ws, out, kind - 12, n, m);
  else if (kind < 36) do_pair<5>(w0, b0, w1, b1, ws, out, kind - 21, n, m);
  else if (kind < 41) do_pair<6>(w0, b0, w1, b1, ws, out, kind - 36, n, m);
  else if (kind < 56) do_pair<7>(w0, b0, w1, b1, ws, out, kind - 41, n, m);
  else                do_pair<8>(w0, b0, w1, b1, ws, out, kind - 56, n, m);
}

// ============================================================================
// Fallback (R7): full-path body with inline preamble, 21-kind fused launch.
// Used only if ws_size is too small for staging.
// ============================================================================
template <int P>
DEV void do_path(const float* __restrict__ diff,
                 const float* __restrict__ w0g, const float* __restrict__ b0g,
                 const float* __restrict__ w1g, const float* __restrict__ b1g,
                 const float* __restrict__ Q, float* __restrict__ out,
                 int a0, int na, int n, int m) {
  constexpr int LO = P / 3, LI = P % 3;
  constexpr int DO = 2 * LO + 1, DI = 2 * LI + 1;
  constexpr int JS = (LO > LI) ? (LO - LI) : (LI - LO);
  constexpr int NJ = 2 * ((LO < LI) ? LO : LI) + 1;
  constexpr int BEL = 4 * NJ;
  constexpr int ROFF = (LO == 0) ? 0 : ((LO == 1) ? 4 : 16);
  constexpr int COFF = (LI == 0) ? 0 : ((LI == 1) ? 4 : 16);
  constexpr int W0OFF = PW0[P];
  constexpr int QOFF  = PQOFF[P];
  const float FV0 = sqrtf((float)DO / (10.0f * (float)BEL * 9.0f));
  const float FV1 = sqrtf((float)DO / 360.0f);

  const float* dp = diff + (((size_t)n << 8) + (size_t)m) * 3;
  const float dx = dp[0], dy = dp[1], dz = dp[2];
  const float r2 = dx * dx + dy * dy + dz * dz;
  const float r  = sqrtf(r2);
  const float rr = fmaxf(r, 1e-8f);
  const float inv = 1.0f / rr;
  const float x = dx * inv, y = dy * inv, z = dz * inv;

  float wv[4];
  {
    const float NORMC = 0.6649038006690546f;
    const float RAD[4] = {0.5f, 1.0f, 1.5f, 2.0f};
#pragma unroll
    for (int k = 0; k < 4; ++k) {
      float tq = (r - RAD[k]) * (1.0f / 0.6f);
      wv[k] = expf(-0.5f * tq * tq) * (NORMC * FV0);
    }
  }
  float Y[25];
  {
    const float A1 = x,                 B1 = y * A1;
    const float A2 = x * A1 - y * B1,   B2 = x * B1 + y * A2;
    const float A3 = x * A2 - y * B2,   B3 = x * B2 + y * A3;
    const float A4 = x * A3 - y * B3,   B4 = x * B3 + y * A4;
    const float z2 = z * z;
    Y[0]  = 0.28209479177387814f;
    Y[1]  = 0.4886025119029199f * B1;
    Y[2]  = 0.4886025119029199f * z;
    Y[3]  = 0.4886025119029199f * A1;
    Y[4]  = 0.5462742152960396f * B2;
    Y[5]  = 1.0925484305920792f * z * B1;
    Y[6]  = 0.31539156525252005f * (3.0f * z2 - 1.0f);
    Y[7]  = 1.0925484305920792f * z * A1;
    Y[8]  = 0.5462742152960396f * A2;
    Y[9]  = 0.5900435899266435f * B3;
    Y[10] = 1.445305721320277f * z * B2;
    Y[11] = 0.4570457994644658f * (5.0f * z2 - 1.0f) * B1;
    Y[12] = 0.3731763325901154f * z * (5.0f * z2 - 3.0f);
    Y[13] = 0.4570457994644658f * (5.0f * z2 - 1.0f) * A1;
    Y[14] = 1.445305721320277f * z * A2;
    Y[15] = 0.5900435899266435f * A3;
    Y[16] = 0.6258357354491761f * B4;
    Y[17] = 1.7701307697799304f * z * B3;
    Y[18] = 0.47308734787878004f * (7.0f * z2 - 1.0f) * B2;
    Y[19] = 0.6690465435572892f * z * (7.0f * z2 - 3.0f) * B1;
    Y[20] = 0.10578554691520431f * ((35.0f * z2 - 30.0f) * z2 + 3.0f);
    Y[21] = 0.6690465435572892f * z * (7.0f * z2 - 3.0f) * A1;
    Y[22] = 0.47308734787878004f * (7.0f * z2 - 1.0f) * A2;
    Y[23] = 1.7701307697799304f * z * A3;
    Y[24] = 0.6258357354491761f * A4;
  }

  float c[10][NJ];
#pragma unroll
  for (int t = 0; t < 10; ++t) {
#pragma unroll
    for (int j = 0; j < NJ; ++j) {
      float acc = 0.0f;
#pragma unroll
      for (int rx = 0; rx < 4; ++rx)
        acc = fmaf(w0g[W0OFF + t * BEL + rx * NJ + j], wv[rx], acc);
      c[t][j] = acc;
    }
  }
  float b0v[10];
#pragma unroll
  for (int t = 0; t < 10; ++t) b0v[t] = b0g[10 * P + t];

  float* __restrict__ outn = out + ((size_t)n << 8);
  const float* __restrict__ w1p = w1g + 160 * P;
  const float* __restrict__ b1p = b1g + 16 * P;

#pragma unroll 1
  for (int ai = 0; ai < na; ++ai) {
    const int a = a0 + ai;
#pragma unroll 1
    for (int b = 0; b < DI; ++b) {
      float K[NJ];
#pragma unroll
      for (int j = 0; j < NJ; ++j) {
        const int W = 2 * (JS + j) + 1;
        const int qbase = QOFF + qlocal(DO, DI, JS, j) + (a * DI + b) * W;
        float acc = 0.0f;
#pragma unroll
        for (int cc = 0; cc < 2 * (JS + j) + 1; ++cc)
          acc = fmaf(Q[qbase + cc], Y[YBASE[JS + j] + cc], acc);
        K[j] = acc;
      }
      float h[10];
#pragma unroll
      for (int t = 0; t < 10; ++t) {
        float acc = b0v[t];
#pragma unroll
        for (int j = 0; j < NJ; ++j) acc = fmaf(c[t][j], K[j], acc);
        h[t] = fmaxf(acc, 0.0f);
      }
#pragma unroll
      for (int u = 0; u < 4; ++u) {
        const int Rr = ROFF + u * DO + a;
#pragma unroll
        for (int v = 0; v < 4; ++v) {
          const int uv = u * 4 + v;
          float acc = 0.0f;
#pragma unroll
          for (int t = 0; t < 10; ++t)
            acc = fmaf(w1p[uv * 10 + t], h[t], acc);
          const float val = fmaf(acc, FV1, b1p[uv]);
          const int Cc = COFF + v * DI + b;
          float* __restrict__ op = outn + (((size_t)(Rr * 36 + Cc)) << 16);
          op[m] = val;
        }
      }
    }
  }
}

__global__ __launch_bounds__(256) void se3_all_kernel(
    const float* __restrict__ diff, const float* __restrict__ w0,
    const float* __restrict__ b0, const float* __restrict__ w1,
    const float* __restrict__ b1, const float* __restrict__ Q,
    float* __restrict__ out) {
  const int kind = blockIdx.x % 21;
  const int n    = blockIdx.x / 21;
  const int m    = threadIdx.x;
  switch (kind) {
    case 0: case 1: case 2: case 3: case 4:
      do_path<8>(diff, w0, b0, w1, b1, Q, out, kind, 1, n, m); break;
    case 5: case 6: case 7: case 8: case 9:
      do_path<7>(diff, w0, b0, w1, b1, Q, out, kind - 5, 1, n, m); break;
    case 10: case 11: case 12:
      do_path<5>(diff, w0, b0, w1, b1, Q, out, kind - 10, 1, n, m); break;
    case 13: case 14: case 15:
      do_path<4>(diff, w0, b0, w1, b1, Q, out, kind - 13, 1, n, m); break;
    case 16: do_path<0>(diff, w0, b0, w1, b1, Q, out, 0, 1, n, m); break;
    case 17: do_path<1>(diff, w0, b0, w1, b1, Q, out, 0, 1, n, m); break;
    case 18: do_path<2>(diff, w0, b0, w1, b1, Q, out, 0, 1, n, m); break;
    case 19: do_path<3>(diff, w0, b0, w1, b1, Q, out, 0, 3, n, m); break;
    case 20: do_path<6>(diff, w0, b0, w1, b1, Q, out, 0, 5, n, m); break;
  }
}

extern "C" void kernel_launch(void* const* d_in, const int* in_sizes, int n_in,
                              void* d_out, int out_size, void* d_ws, size_t ws_size,
                              hipStream_t stream) {
  const float* diff = (const float*)d_in[0];
  const float* w0   = (const float*)d_in[1];
  const float* b0   = (const float*)d_in[2];
  const float* w1   = (const float*)d_in[3];
  const float* b1   = (const float*)d_in[4];
  float* out = (float*)d_out;
  float* qws = (float*)d_ws;  // [0..1225) Q; [2048..) staged planes (rebuilt every call)

  init_q_kernel<<<dim3(19), dim3(256), 0, stream>>>(qws);

  const size_t NEED = (size_t)(WSY + 29 * PLANE) * sizeof(float);  // ~7.61 MB
  if (ws_size >= NEED) {
    se3_stage1<<<dim3(256), dim3(256), 0, stream>>>(diff, qws);
    se3_stage2<<<dim3(81 * 256), dim3(256), 0, stream>>>(w0, b0, w1, b1, qws, out);
  } else {
    se3_all_kernel<<<dim3(21 * 256), dim3(256), 0, stream>>>(diff, w0, b0, w1, b1, qws, out);
  }
}

// Round 9
// 361.708 us; speedup vs baseline: 1.8526x; 1.0715x over previous
//
#include <hip/hip_runtime.h>

// ============================================================================
// SE3 two-layer point kernel, MI355X (gfx950)
// Output: (36,36,256,256) fp32, ~340 MB -> HBM-write floor ~54us (+~225us
// harness re-poison fill we cannot control).
//
// R9: COMPILE-TIME Q TABLES (constexpr Clebsch-Gordan) + keep R8 structure.
//   R8 (fine-grained (path,a,b) blocks + staged basis) was the first big win:
//   448 -> 388us. Remaining visible non-floor costs: init_q (19-block fp64
//   kernel, latency-bound dfact/cgc chains, runs EVERY call), one launch
//   boundary, and Q loads via VMEM. The 19 Q tables depend only on
//   compile-time constants -> compute them constexpr (factorial LUT +
//   scaled-Newton csqrt; one constexpr variable per table to stay under
//   clang's constexpr-step limit) into a 4.9KB __constant__ array.
//   Deletes the init_q launch, makes Q reads scalar constant-cache loads.
//   Numerics: Q may shift <=1ulp (Newton sqrt vs device sqrt) -- far under
//   the passing 0.00195 tolerance.
// ============================================================================

#define DEV __device__ __forceinline__

// ----- compile-time path metadata: path p = lo*3 + li ------------------------
constexpr int PW0[9]   = {0,40,80,120,160,280,400,440,560};   // weight_0 offsets
constexpr int PQOFF[9] = {0,1,10,35,44,125,350,375,600};      // Q table base (floats)
constexpr int YBASE[5] = {0,1,4,9,16};                        // Y row offset per J

__host__ __device__ constexpr int qlocal(int DO, int DI, int JS, int j) {
  int o = 0;
  for (int k = 0; k < j; ++k) o += DO * DI * (2 * (JS + k) + 1);
  return o;
}

// ws layout: staged planes only, stride 65536 floats:
//   planes 0-3: windows (exp * NORMC, unscaled by fv0); planes 4-28: Y[0..25)
constexpr int PLANE = 65536;

// ============================================================================
// Compile-time Q tables (replaces the init_q kernel)
// ============================================================================
constexpr double CFACT[12] = {1.0, 1.0, 2.0, 6.0, 24.0, 120.0, 720.0,
                              5040.0, 40320.0, 362880.0, 3628800.0, 39916800.0};

constexpr double csqrt(double a) {
  if (a <= 0.0) return 0.0;
  double m = a, scale = 1.0;
  while (m >= 4.0) { m *= 0.25; scale *= 2.0; }
  while (m < 1.0)  { m *= 4.0;  scale *= 0.5; }
  double x = 1.5;
  for (int i = 0; i < 8; ++i) x = 0.5 * (x + m / x);
  return x * scale;
}

constexpr double ccgc(int l1, int m1, int l2, int m2, int l3, int m3) {
  if (m1 + m2 != m3) return 0.0;
  double pre = csqrt((2.0 * l3 + 1.0) * CFACT[l3 + l1 - l2] * CFACT[l3 - l1 + l2] *
                     CFACT[l1 + l2 - l3] / CFACT[l1 + l2 + l3 + 1]);
  pre *= csqrt(CFACT[l3 + m3] * CFACT[l3 - m3] * CFACT[l1 - m1] * CFACT[l1 + m1] *
               CFACT[l2 - m2] * CFACT[l2 + m2]);
  double s = 0.0;
  for (int k = 0; k <= l1 + l2 - l3; ++k) {
    int d1 = l1 + l2 - l3 - k, d2 = l1 - m1 - k, d3 = l2 + m2 - k;
    int d4 = l3 - l2 + m1 + k, d5 = l3 - l1 - m2 + k;
    if (d1 < 0 || d2 < 0 || d3 < 0 || d4 < 0 || d5 < 0) continue;
    double term = 1.0 / (CFACT[k] * CFACT[d1] * CFACT[d2] * CFACT[d3] * CFACT[d4] * CFACT[d5]);
    s += (k & 1) ? -term : term;
  }
  return pre * s;
}

struct URow { int n; int col[2]; double re[2]; double im[2]; };
constexpr URow curow(int l, int a) {
  URow u{};
  const double RS = 0.7071067811865476;
  int m = a - l;
  if (m == 0) { u.n = 1; u.col[0] = l; u.re[0] = 1.0; u.im[0] = 0.0; return u; }
  if (m > 0) {
    double s = (m & 1) ? -1.0 : 1.0;
    u.n = 2; u.col[0] = l + m; u.re[0] = s * RS; u.im[0] = 0.0;
    u.col[1] = l - m; u.re[1] = RS; u.im[1] = 0.0;
    return u;
  }
  int mm = -m;
  double s = (mm & 1) ? -1.0 : 1.0;
  u.n = 2; u.col[0] = l + mm; u.re[0] = 0.0; u.im[0] = -s * RS;
  u.col[1] = l - mm; u.re[1] = 0.0; u.im[1] = RS;
  return u;
}

struct QT { float v[225]; };
constexpr QT make_table(int lo, int li, int J) {
  QT out{};
  const int d_o = 2 * lo + 1, d_i = 2 * li + 1, w = 2 * J + 1;
  const int size = d_o * d_i * w;
  double tre[225] = {}, tim[225] = {};
  double sre = 0.0, sim = 0.0;
  for (int e = 0; e < size; ++e) {
    int row = e / w, cc = e % w;
    int a = row / d_i, b = row % d_i;
    URow uo = curow(lo, a), ui = curow(li, b), uj = curow(J, cc);
    double re = 0.0, im = 0.0;
    for (int i0 = 0; i0 < uo.n; ++i0)
      for (int i1 = 0; i1 < ui.n; ++i1)
        for (int i2 = 0; i2 < uj.n; ++i2) {
          double cg = ccgc(li, ui.col[i1] - li, J, uj.col[i2] - J, lo, uo.col[i0] - lo);
          if (cg == 0.0) continue;
          double ar = uo.re[i0], ai = uo.im[i0];
          double br = ui.re[i1], bi = -ui.im[i1];   // conj
          double cr = uj.re[i2], cii = -uj.im[i2];  // conj
          double abr = ar * br - ai * bi, abi = ar * bi + ai * br;
          double pr = abr * cr - abi * cii, pi = abr * cii + abi * cr;
          re += pr * cg; im += pi * cg;
        }
    tre[e] = re; tim[e] = im;
    sre += (re < 0.0 ? -re : re);
    sim += (im < 0.0 ? -im : im);
  }
  for (int e = 0; e < size; ++e) out.v[e] = (float)((sre >= sim) ? tre[e] : tim[e]);
  return out;
}

// one constexpr variable per table (separate constexpr evaluations)
constexpr QT qt00 = make_table(0,0,0);
constexpr QT qt01 = make_table(0,1,1);
constexpr QT qt02 = make_table(0,2,2);
constexpr QT qt03 = make_table(1,0,1);
constexpr QT qt04 = make_table(1,1,0);
constexpr QT qt05 = make_table(1,1,1);
constexpr QT qt06 = make_table(1,1,2);
constexpr QT qt07 = make_table(1,2,1);
constexpr QT qt08 = make_table(1,2,2);
constexpr QT qt09 = make_table(1,2,3);
constexpr QT qt10 = make_table(2,0,2);
constexpr QT qt11 = make_table(2,1,1);
constexpr QT qt12 = make_table(2,1,2);
constexpr QT qt13 = make_table(2,1,3);
constexpr QT qt14 = make_table(2,2,0);
constexpr QT qt15 = make_table(2,2,1);
constexpr QT qt16 = make_table(2,2,2);
constexpr QT qt17 = make_table(2,2,3);
constexpr QT qt18 = make_table(2,2,4);

struct QTab { float v[1225]; };
constexpr QTab make_all() {
  QTab A{};
  const QT* ts[19] = {&qt00,&qt01,&qt02,&qt03,&qt04,&qt05,&qt06,&qt07,&qt08,&qt09,
                      &qt10,&qt11,&qt12,&qt13,&qt14,&qt15,&qt16,&qt17,&qt18};
  const int T_LO[19]  = {0,0,0, 1, 1,1,1, 1,1,1, 2, 2,2,2, 2,2,2,2,2};
  const int T_LI[19]  = {0,1,2, 0, 1,1,1, 2,2,2, 0, 1,1,1, 2,2,2,2,2};
  const int T_J [19]  = {0,1,2, 1, 0,1,2, 1,2,3, 2, 1,2,3, 0,1,2,3,4};
  const int T_OFF[19] = {0,1,10,35,44,53,80,125,170,245,350,375,420,495,600,625,700,825,1000};
  for (int t = 0; t < 19; ++t) {
    const int size = (2*T_LO[t]+1) * (2*T_LI[t]+1) * (2*T_J[t]+1);
    for (int e = 0; e < size; ++e) A.v[T_OFF[t] + e] = ts[t]->v[e];
  }
  return A;
}
constexpr QTab QALL_H = make_all();
__constant__ QTab QC = QALL_H;

// ============================================================================
// Stage 1: per-point windows (exp*NORMC) + Y[25] -> ws planes (SoA, coalesced)
// ============================================================================
__global__ __launch_bounds__(256) void se3_stage1(const float* __restrict__ diff,
                                                  float* __restrict__ ws) {
  const int n = blockIdx.x, m = threadIdx.x;
  const int nm = (n << 8) | m;
  const float* dp = diff + (size_t)nm * 3;
  const float dx = dp[0], dy = dp[1], dz = dp[2];
  const float r2 = dx * dx + dy * dy + dz * dz;
  const float r  = sqrtf(r2);
  const float rr = fmaxf(r, 1e-8f);
  const float inv = 1.0f / rr;
  const float x = dx * inv, y = dy * inv, z = dz * inv;

  float* base = ws + nm;

  {
    const float NORMC = 0.6649038006690546f;  // 1/(0.6*sqrt(2pi))
    const float RAD[4] = {0.5f, 1.0f, 1.5f, 2.0f};
#pragma unroll
    for (int k = 0; k < 4; ++k) {
      float tq = (r - RAD[k]) * (1.0f / 0.6f);
      base[(size_t)k * PLANE] = expf(-0.5f * tq * tq) * NORMC;
    }
  }
  {
    const float A1 = x,                 B1 = y * A1;
    const float A2 = x * A1 - y * B1,   B2 = x * B1 + y * A2;
    const float A3 = x * A2 - y * B2,   B3 = x * B2 + y * A3;
    const float A4 = x * A3 - y * B3,   B4 = x * B3 + y * A4;
    const float z2 = z * z;
    float Y[25];
    Y[0]  = 0.28209479177387814f;
    Y[1]  = 0.4886025119029199f * B1;
    Y[2]  = 0.4886025119029199f * z;
    Y[3]  = 0.4886025119029199f * A1;
    Y[4]  = 0.5462742152960396f * B2;
    Y[5]  = 1.0925484305920792f * z * B1;
    Y[6]  = 0.31539156525252005f * (3.0f * z2 - 1.0f);
    Y[7]  = 1.0925484305920792f * z * A1;
    Y[8]  = 0.5462742152960396f * A2;
    Y[9]  = 0.5900435899266435f * B3;
    Y[10] = 1.445305721320277f * z * B2;
    Y[11] = 0.4570457994644658f * (5.0f * z2 - 1.0f) * B1;
    Y[12] = 0.3731763325901154f * z * (5.0f * z2 - 3.0f);
    Y[13] = 0.4570457994644658f * (5.0f * z2 - 1.0f) * A1;
    Y[14] = 1.445305721320277f * z * A2;
    Y[15] = 0.5900435899266435f * A3;
    Y[16] = 0.6258357354491761f * B4;
    Y[17] = 1.7701307697799304f * z * B3;
    Y[18] = 0.47308734787878004f * (7.0f * z2 - 1.0f) * B2;
    Y[19] = 0.6690465435572892f * z * (7.0f * z2 - 3.0f) * B1;
    Y[20] = 0.10578554691520431f * ((35.0f * z2 - 30.0f) * z2 + 3.0f);
    Y[21] = 0.6690465435572892f * z * (7.0f * z2 - 3.0f) * A1;
    Y[22] = 0.47308734787878004f * (7.0f * z2 - 1.0f) * A2;
    Y[23] = 1.7701307697799304f * z * A3;
    Y[24] = 0.6258357354491761f * A4;
#pragma unroll
    for (int i = 0; i < 25; ++i) base[(size_t)(4 + i) * PLANE] = Y[i];
  }
}

// ============================================================================
// Stage 2 body: ONE (path, a, b) pair for point (n, m). Tiny live set.
// ============================================================================
template <int P>
DEV void do_pair(const float* __restrict__ w0g, const float* __restrict__ b0g,
                 const float* __restrict__ w1g, const float* __restrict__ b1g,
                 const float* __restrict__ ws, float* __restrict__ out,
                 int ab, int n, int m) {
  constexpr int LO = P / 3, LI = P % 3;
  constexpr int DO = 2 * LO + 1, DI = 2 * LI + 1;
  constexpr int JS = (LO > LI) ? (LO - LI) : (LI - LO);
  constexpr int NJ = 2 * ((LO < LI) ? LO : LI) + 1;
  constexpr int BEL = 4 * NJ;
  constexpr int ROFF = (LO == 0) ? 0 : ((LO == 1) ? 4 : 16);
  constexpr int COFF = (LI == 0) ? 0 : ((LI == 1) ? 4 : 16);
  constexpr int W0OFF = PW0[P];
  constexpr int QOFF  = PQOFF[P];
  constexpr int YLO = YBASE[JS];                                   // first Y row used
  constexpr int YHI = YBASE[JS + NJ - 1] + 2 * (JS + NJ - 1) + 1;  // one past last
  const float FV0 = sqrtf((float)DO / (10.0f * (float)BEL * 9.0f));
  const float FV1 = sqrtf((float)DO / 360.0f);

  const int nm = (n << 8) | m;
  const float* __restrict__ sb = ws + nm;

  // staged loads: windows (fold fv0) + needed Y rows. Coalesced along m.
  float wvs[4];
#pragma unroll
  for (int k = 0; k < 4; ++k) wvs[k] = sb[(size_t)k * PLANE] * FV0;
  float Yv[YHI - YLO];
#pragma unroll
  for (int i = 0; i < YHI - YLO; ++i) Yv[i] = sb[(size_t)(4 + YLO + i) * PLANE];

  const int a = ab / DI, b = ab - a * DI;

  // K[j] = Q_row(a,b) . Y_J   (Q from __constant__ -> scalar loads)
  float K[NJ];
#pragma unroll
  for (int j = 0; j < NJ; ++j) {
    const int W = 2 * (JS + j) + 1;
    const int qbase = QOFF + qlocal(DO, DI, JS, j) + ab * W;
    float acc = 0.0f;
#pragma unroll
    for (int cc = 0; cc < 2 * (JS + j) + 1; ++cc)
      acc = fmaf(QC.v[qbase + cc], Yv[YBASE[JS + j] - YLO + cc], acc);
    K[j] = acc;
  }

  // layer 0: h[t] = b0[t] + sum_j (sum_r w0[t,r,j]*wvs[r]) * K[j]
  const float* __restrict__ b0p = b0g + 10 * P;
  float h[10];
#pragma unroll
  for (int t = 0; t < 10; ++t) {
    float acc = b0p[t];
#pragma unroll
    for (int j = 0; j < NJ; ++j) {
      float cj = w0g[W0OFF + t * BEL + 0 * NJ + j] * wvs[0];
#pragma unroll
      for (int rx = 1; rx < 4; ++rx)
        cj = fmaf(w0g[W0OFF + t * BEL + rx * NJ + j], wvs[rx], cj);
      acc = fmaf(cj, K[j], acc);
    }
    h[t] = fmaxf(acc, 0.0f);
  }

  // layer 1 + 16 coalesced stores
  const float* __restrict__ w1p = w1g + 160 * P;
  const float* __restrict__ b1p = b1g + 16 * P;
  float* __restrict__ outn = out + ((size_t)n << 8);
#pragma unroll
  for (int u = 0; u < 4; ++u) {
    const int Rr = ROFF + u * DO + a;
#pragma unroll
    for (int v = 0; v < 4; ++v) {
      const int uv = u * 4 + v;
      float acc = 0.0f;
#pragma unroll
      for (int t = 0; t < 10; ++t)
        acc = fmaf(w1p[uv * 10 + t], h[t], acc);
      const float val = fmaf(acc, FV1, b1p[uv]);
      const int Cc = COFF + v * DI + b;
      float* __restrict__ op = outn + (((size_t)(Rr * 36 + Cc)) << 16);
      op[m] = val;
    }
  }
}

// 81 kinds: p0:[0,1) p1:[1,4) p2:[4,9) p3:[9,12) p4:[12,21) p5:[21,36)
//           p6:[36,41) p7:[41,56) p8:[56,81)
__global__ __launch_bounds__(256) void se3_stage2(
    const float* __restrict__ w0, const float* __restrict__ b0,
    const float* __restrict__ w1, const float* __restrict__ b1,
    const float* __restrict__ ws, float* __restrict__ out) {
  const int kind = blockIdx.x % 81;
  const int n    = blockIdx.x / 81;
  const int m    = threadIdx.x;
  if      (kind < 1)  do_pair<0>(w0, b0, w1, b1, ws, out, kind,      n, m);
  else if (kind < 4)  do_pair<1>(w0, b0, w1, b1, ws, out, kind - 1,  n, m);
  else if (kind < 9)  do_pair<2>(w0, b0, w1, b1, ws, out, kind - 4,  n, m);
  else if (kind < 12) do_pair<3>(w0, b0, w1, b1, ws, out, kind - 9,  n, m);
  else if (kind < 21) do_pair<4>(w0, b0, w1, b1, ws, out, kind - 12, n, m);
  else if (kind < 36) do_pair<5>(w0, b0, w1, b1, ws, out, kind - 21, n, m);
  else if (kind < 41) do_pair<6>(w0, b0, w1, b1, ws, out, kind - 36, n, m);
  else if (kind < 56) do_pair<7>(w0, b0, w1, b1, ws, out, kind - 41, n, m);
  else                do_pair<8>(w0, b0, w1, b1, ws, out, kind - 56, n, m);
}

// ============================================================================
// Fallback: full-path body with inline preamble (no ws use), 21-kind launch.
// Used only if ws_size is too small for staging.
// ============================================================================
template <int P>
DEV void do_path(const float* __restrict__ diff,
                 const float* __restrict__ w0g, const float* __restrict__ b0g,
                 const float* __restrict__ w1g, const float* __restrict__ b1g,
                 float* __restrict__ out, int a0, int na, int n, int m) {
  constexpr int LO = P / 3, LI = P % 3;
  constexpr int DO = 2 * LO + 1, DI = 2 * LI + 1;
  constexpr int JS = (LO > LI) ? (LO - LI) : (LI - LO);
  constexpr int NJ = 2 * ((LO < LI) ? LO : LI) + 1;
  constexpr int BEL = 4 * NJ;
  constexpr int ROFF = (LO == 0) ? 0 : ((LO == 1) ? 4 : 16);
  constexpr int COFF = (LI == 0) ? 0 : ((LI == 1) ? 4 : 16);
  constexpr int W0OFF = PW0[P];
  constexpr int QOFF  = PQOFF[P];
  const float FV0 = sqrtf((float)DO / (10.0f * (float)BEL * 9.0f));
  const float FV1 = sqrtf((float)DO / 360.0f);

  const float* dp = diff + (((size_t)n << 8) + (size_t)m) * 3;
  const float dx = dp[0], dy = dp[1], dz = dp[2];
  const float r2 = dx * dx + dy * dy + dz * dz;
  const float r  = sqrtf(r2);
  const float rr = fmaxf(r, 1e-8f);
  const float inv = 1.0f / rr;
  const float x = dx * inv, y = dy * inv, z = dz * inv;

  float wv[4];
  {
    const float NORMC = 0.6649038006690546f;
    const float RAD[4] = {0.5f, 1.0f, 1.5f, 2.0f};
#pragma unroll
    for (int k = 0; k < 4; ++k) {
      float tq = (r - RAD[k]) * (1.0f / 0.6f);
      wv[k] = expf(-0.5f * tq * tq) * (NORMC * FV0);
    }
  }
  float Y[25];
  {
    const float A1 = x,                 B1 = y * A1;
    const float A2 = x * A1 - y * B1,   B2 = x * B1 + y * A2;
    const float A3 = x * A2 - y * B2,   B3 = x * B2 + y * A3;
    const float A4 = x * A3 - y * B3,   B4 = x * B3 + y * A4;
    const float z2 = z * z;
    Y[0]  = 0.28209479177387814f;
    Y[1]  = 0.4886025119029199f * B1;
    Y[2]  = 0.4886025119029199f * z;
    Y[3]  = 0.4886025119029199f * A1;
    Y[4]  = 0.5462742152960396f * B2;
    Y[5]  = 1.0925484305920792f * z * B1;
    Y[6]  = 0.31539156525252005f * (3.0f * z2 - 1.0f);
    Y[7]  = 1.0925484305920792f * z * A1;
    Y[8]  = 0.5462742152960396f * A2;
    Y[9]  = 0.5900435899266435f * B3;
    Y[10] = 1.445305721320277f * z * B2;
    Y[11] = 0.4570457994644658f * (5.0f * z2 - 1.0f) * B1;
    Y[12] = 0.3731763325901154f * z * (5.0f * z2 - 3.0f);
    Y[13] = 0.4570457994644658f * (5.0f * z2 - 1.0f) * A1;
    Y[14] = 1.445305721320277f * z * A2;
    Y[15] = 0.5900435899266435f * A3;
    Y[16] = 0.6258357354491761f * B4;
    Y[17] = 1.7701307697799304f * z * B3;
    Y[18] = 0.47308734787878004f * (7.0f * z2 - 1.0f) * B2;
    Y[19] = 0.6690465435572892f * z * (7.0f * z2 - 3.0f) * B1;
    Y[20] = 0.10578554691520431f * ((35.0f * z2 - 30.0f) * z2 + 3.0f);
    Y[21] = 0.6690465435572892f * z * (7.0f * z2 - 3.0f) * A1;
    Y[22] = 0.47308734787878004f * (7.0f * z2 - 1.0f) * A2;
    Y[23] = 1.7701307697799304f * z * A3;
    Y[24] = 0.6258357354491761f * A4;
  }

  float c[10][NJ];
#pragma unroll
  for (int t = 0; t < 10; ++t) {
#pragma unroll
    for (int j = 0; j < NJ; ++j) {
      float acc = 0.0f;
#pragma unroll
      for (int rx = 0; rx < 4; ++rx)
        acc = fmaf(w0g[W0OFF + t * BEL + rx * NJ + j], wv[rx], acc);
      c[t][j] = acc;
    }
  }
  float b0v[10];
#pragma unroll
  for (int t = 0; t < 10; ++t) b0v[t] = b0g[10 * P + t];

  float* __restrict__ outn = out + ((size_t)n << 8);
  const float* __restrict__ w1p = w1g + 160 * P;
  const float* __restrict__ b1p = b1g + 16 * P;

#pragma unroll 1
  for (int ai = 0; ai < na; ++ai) {
    const int a = a0 + ai;
#pragma unroll 1
    for (int b = 0; b < DI; ++b) {
      float K[NJ];
#pragma unroll
      for (int j = 0; j < NJ; ++j) {
        const int W = 2 * (JS + j) + 1;
        const int qbase = QOFF + qlocal(DO, DI, JS, j) + (a * DI + b) * W;
        float acc = 0.0f;
#pragma unroll
        for (int cc = 0; cc < 2 * (JS + j) + 1; ++cc)
          acc = fmaf(QC.v[qbase + cc], Y[YBASE[JS + j] + cc], acc);
        K[j] = acc;
      }
      float h[10];
#pragma unroll
      for (int t = 0; t < 10; ++t) {
        float acc = b0v[t];
#pragma unroll
        for (int j = 0; j < NJ; ++j) acc = fmaf(c[t][j], K[j], acc);
        h[t] = fmaxf(acc, 0.0f);
      }
#pragma unroll
      for (int u = 0; u < 4; ++u) {
        const int Rr = ROFF + u * DO + a;
#pragma unroll
        for (int v = 0; v < 4; ++v) {
          const int uv = u * 4 + v;
          float acc = 0.0f;
#pragma unroll
          for (int t = 0; t < 10; ++t)
            acc = fmaf(w1p[uv * 10 + t], h[t], acc);
          const float val = fmaf(acc, FV1, b1p[uv]);
          const int Cc = COFF + v * DI + b;
          float* __restrict__ op = outn + (((size_t)(Rr * 36 + Cc)) << 16);
          op[m] = val;
        }
      }
    }
  }
}

__global__ __launch_bounds__(256) void se3_all_kernel(
    const float* __restrict__ diff, const float* __restrict__ w0,
    const float* __restrict__ b0, const float* __restrict__ w1,
    const float* __restrict__ b1, float* __restrict__ out) {
  const int kind = blockIdx.x % 21;
  const int n    = blockIdx.x / 21;
  const int m    = threadIdx.x;
  switch (kind) {
    case 0: case 1: case 2: case 3: case 4:
      do_path<8>(diff, w0, b0, w1, b1, out, kind, 1, n, m); break;
    case 5: case 6: case 7: case 8: case 9:
      do_path<7>(diff, w0, b0, w1, b1, out, kind - 5, 1, n, m); break;
    case 10: case 11: case 12:
      do_path<5>(diff, w0, b0, w1, b1, out, kind - 10, 1, n, m); break;
    case 13: case 14: case 15:
      do_path<4>(diff, w0, b0, w1, b1, out, kind - 13, 1, n, m); break;
    case 16: do_path<0>(diff, w0, b0, w1, b1, out, 0, 1, n, m); break;
    case 17: do_path<1>(diff, w0, b0, w1, b1, out, 0, 1, n, m); break;
    case 18: do_path<2>(diff, w0, b0, w1, b1, out, 0, 1, n, m); break;
    case 19: do_path<3>(diff, w0, b0, w1, b1, out, 0, 3, n, m); break;
    case 20: do_path<6>(diff, w0, b0, w1, b1, out, 0, 5, n, m); break;
  }
}

extern "C" void kernel_launch(void* const* d_in, const int* in_sizes, int n_in,
                              void* d_out, int out_size, void* d_ws, size_t ws_size,
                              hipStream_t stream) {
  const float* diff = (const float*)d_in[0];
  const float* w0   = (const float*)d_in[1];
  const float* b0   = (const float*)d_in[2];
  const float* w1   = (const float*)d_in[3];
  const float* b1   = (const float*)d_in[4];
  float* out = (float*)d_out;
  float* sws = (float*)d_ws;  // staged planes only (rebuilt every call)

  const size_t NEED = (size_t)(29 * PLANE) * sizeof(float);  // ~7.6 MB
  if (ws_size >= NEED) {
    se3_stage1<<<dim3(256), dim3(256), 0, stream>>>(diff, sws);
    se3_stage2<<<dim3(81 * 256), dim3(256), 0, stream>>>(w0, b0, w1, b1, sws, out);
  } else {
    se3_all_kernel<<<dim3(21 * 256), dim3(256), 0, stream>>>(diff, w0, b0, w1, b1, out);
  }
}